// Round 1
// baseline (120.497 us; speedup 1.0000x reference)
//
#include <hip/hip_runtime.h>

// Problem constants
#define D_K   1024      // hidden dim (GEMM K)
#define ROWS  16384     // B*L
#define MLP   500
#define NPAD  1024      // padded combined N: [0,512)=dep, [512,1024)=head
#define NEG   0.01f

typedef __bf16 bf16x8 __attribute__((ext_vector_type(8)));
typedef float  f32x4  __attribute__((ext_vector_type(4)));

#define GL(p) ((const __attribute__((address_space(1))) void*)(p))
#define LD(p) ((__attribute__((address_space(3))) void*)(p))

__device__ __forceinline__ ushort f2bf(float f) {
    union { float f; unsigned u; } v; v.f = f;
    unsigned u = v.u;
    unsigned r = (u + 0x7FFFu + ((u >> 16) & 1u)) >> 16;   // RNE
    return (ushort)r;
}

// ---------------- hidden f32 -> bf16 ----------------
__global__ __launch_bounds__(256) void conv_hidden(const float4* __restrict__ in,
                                                   ushort* __restrict__ out, int n4) {
    for (int i = blockIdx.x * blockDim.x + threadIdx.x; i < n4; i += gridDim.x * blockDim.x) {
        float4 f = in[i];
        ushort4 o;
        o.x = f2bf(f.x); o.y = f2bf(f.y); o.z = f2bf(f.z); o.w = f2bf(f.w);
        ((ushort4*)out)[i] = o;
    }
}

// ---------------- W [1024][500] -> Bt bf16 [NPAD][1024] (transposed, padded) ----------------
__global__ __launch_bounds__(256) void conv_w(const float* __restrict__ Wd,
                                              const float* __restrict__ Wh,
                                              ushort* __restrict__ Bt) {
    __shared__ ushort t[64][72];
    const float* W = blockIdx.z ? Wh : Wd;
    int k0 = blockIdx.x * 64, n0 = blockIdx.y * 64;
    int c = threadIdx.x & 63, r4 = threadIdx.x >> 6;
    for (int r = r4; r < 64; r += 4) {
        int n = n0 + c;
        float v = (n < MLP) ? W[(size_t)(k0 + r) * MLP + n] : 0.f;  // coalesced read over n
        t[c][r] = f2bf(v);
    }
    __syncthreads();
    int nbase = blockIdx.z * 512 + n0;
    for (int rr = r4; rr < 64; rr += 4)
        Bt[(size_t)(nbase + rr) * D_K + k0 + c] = t[rr][c];          // coalesced write over k
}

// ---------------- pad bias + Wc ----------------
__global__ void prep_small(const float* __restrict__ b_dep, const float* __restrict__ b_head,
                           const float* __restrict__ Wc,
                           float* __restrict__ bias_pad, float* __restrict__ wc_pad) {
    int n = threadIdx.x;  // 1024
    float bv = 0.f, w0 = 0.f, w1 = 0.f;
    if (n < 512) {
        if (n < MLP) { bv = b_dep[n]; w0 = Wc[n * 2]; w1 = Wc[n * 2 + 1]; }
    } else {
        int m = n - 512;
        if (m < MLP) { bv = b_head[m]; w0 = Wc[(MLP + m) * 2]; w1 = Wc[(MLP + m) * 2 + 1]; }
    }
    bias_pad[n] = bv; wc_pad[n * 2] = w0; wc_pad[n * 2 + 1] = w1;
}

// ---------------- fused GEMM + leakyrelu + score reduction ----------------
// C[row, n] = A[row, :] . Bt[n, :];  h = leakyrelu(C + bias[n]);
// scores[row, c] += sum_n h * wc[n, c]   (atomic, per branch)
__global__ __launch_bounds__(256) void gemm_scores(const ushort* __restrict__ A,
                                                   const ushort* __restrict__ Bt,
                                                   const float* __restrict__ bias,
                                                   const float* __restrict__ wc,
                                                   float* __restrict__ sd,
                                                   float* __restrict__ sh) {
    __shared__ ushort As[128 * 64];   // [row][k] 16 KB
    __shared__ ushort Bs[128 * 64];   // [n][k]   16 KB
    const int tid  = threadIdx.x;
    const int lane = tid & 63;
    const int wave = tid >> 6;
    const int wm = wave >> 1, wn = wave & 1;
    const int bn = blockIdx.x, bm = blockIdx.y;   // x = N so consecutive blocks share A panel
    const int row0 = bm * 128, col0 = bn * 128;

    f32x4 acc[4][4] = {};

    const int lr = lane >> 3;          // row within 8-row chunk
    const int lk = (lane & 7) * 8;     // k element offset within chunk

    for (int k0 = 0; k0 < D_K; k0 += 64) {
        // stage A,B tiles: 16 chunks of 1KB each (8 rows x 64 bf16), 4 chunks/wave
#pragma unroll
        for (int i = 0; i < 4; ++i) {
            const int ci = wave + i * 4;
            const ushort* asrc = A + (size_t)(row0 + ci * 8 + lr) * D_K + k0 + lk;
            __builtin_amdgcn_global_load_lds(GL(asrc), LD(&As[ci * 512]), 16, 0, 0);
            const ushort* bsrc = Bt + (size_t)(col0 + ci * 8 + lr) * D_K + k0 + lk;
            __builtin_amdgcn_global_load_lds(GL(bsrc), LD(&Bs[ci * 512]), 16, 0, 0);
        }
        __syncthreads();
#pragma unroll
        for (int ks = 0; ks < 2; ++ks) {
            bf16x8 af[4], bfr[4];
#pragma unroll
            for (int f = 0; f < 4; ++f) {
                af[f]  = *(const bf16x8*)&As[(wm * 64 + f * 16 + (lane & 15)) * 64 + ks * 32 + (lane >> 4) * 8];
                bfr[f] = *(const bf16x8*)&Bs[(wn * 64 + f * 16 + (lane & 15)) * 64 + ks * 32 + (lane >> 4) * 8];
            }
#pragma unroll
            for (int mi = 0; mi < 4; ++mi)
#pragma unroll
                for (int ni = 0; ni < 4; ++ni)
                    acc[mi][ni] = __builtin_amdgcn_mfma_f32_16x16x32_bf16(af[mi], bfr[ni], acc[mi][ni], 0, 0, 0);
        }
        __syncthreads();
    }

    // Epilogue: bias + leakyrelu + rank-2 contraction with wc, then row-reduce.
    // C/D layout: col = lane&15, row = (lane>>4)*4 + reg  [m89-verified]
    float bv[4], w0v[4], w1v[4];
#pragma unroll
    for (int nf = 0; nf < 4; ++nf) {
        int c = col0 + wn * 64 + nf * 16 + (lane & 15);
        bv[nf] = bias[c]; w0v[nf] = wc[2 * c]; w1v[nf] = wc[2 * c + 1];
    }
    float* S = (bn < 4) ? sd : sh;
#pragma unroll
    for (int mf = 0; mf < 4; ++mf) {
        int rowb = row0 + wm * 64 + mf * 16 + (lane >> 4) * 4;
#pragma unroll
        for (int r = 0; r < 4; ++r) {
            float s0 = 0.f, s1 = 0.f;
#pragma unroll
            for (int nf = 0; nf < 4; ++nf) {
                float h = acc[mf][nf][r] + bv[nf];
                h = (h > 0.f) ? h : NEG * h;
                s0 += h * w0v[nf]; s1 += h * w1v[nf];
            }
            // reduce across the 16 lanes sharing this row
#pragma unroll
            for (int m = 1; m < 16; m <<= 1) {
                s0 += __shfl_xor(s0, m, 64);
                s1 += __shfl_xor(s1, m, 64);
            }
            if ((lane & 15) == 0) {
                atomicAdd(&S[(size_t)(rowb + r) * 2 + 0], s0);
                atomicAdd(&S[(size_t)(rowb + r) * 2 + 1], s1);
            }
        }
    }
}

// ---------------- broadcast add: out[b,i,j,c] = sd[b,i,c] + sh[b,j,c] + bc[c] ----------------
__global__ __launch_bounds__(256) void bcast(const float* __restrict__ sd,
                                             const float* __restrict__ sh,
                                             const float* __restrict__ bc,
                                             float* __restrict__ out) {
    int bi = blockIdx.x;            // b*1024 + i
    int b  = bi >> 10;
    float v0 = sd[bi * 2 + 0] + bc[0];
    float v1 = sd[bi * 2 + 1] + bc[1];
    const float4* shrow = (const float4*)(sh + (size_t)b * 2048);
    float4* orow = (float4*)(out + (size_t)bi * 2048);
#pragma unroll
    for (int t = threadIdx.x; t < 512; t += 256) {
        float4 s = shrow[t];
        float4 o;
        o.x = v0 + s.x; o.y = v1 + s.y; o.z = v0 + s.z; o.w = v1 + s.w;
        orow[t] = o;
    }
}

extern "C" void kernel_launch(void* const* d_in, const int* in_sizes, int n_in,
                              void* d_out, int out_size, void* d_ws, size_t ws_size,
                              hipStream_t stream) {
    const float* hs = (const float*)d_in[0];
    const float* Wd = (const float*)d_in[1];
    const float* bd = (const float*)d_in[2];
    const float* Wh = (const float*)d_in[3];
    const float* bh = (const float*)d_in[4];
    const float* Wc = (const float*)d_in[5];
    const float* bc = (const float*)d_in[6];
    float* out = (float*)d_out;

    char* ws = (char*)d_ws;
    ushort* A    = (ushort*)(ws);                 // 16384*1024*2 = 33,554,432 B
    ushort* Bt   = (ushort*)(ws + 33554432);      //  1024*1024*2 =  2,097,152 B
    float*  bias = (float*) (ws + 35651584);      //  4 KB
    float*  wcp  = (float*) (ws + 35655680);      //  8 KB
    float*  sd   = (float*) (ws + 35663872);      //  128 KB
    float*  sh   = (float*) (ws + 35794944);      //  128 KB   (end ≈ 35.9 MB)

    hipMemsetAsync(sd, 0, 262144, stream);        // zero both score arrays (contiguous)

    conv_hidden<<<2048, 256, 0, stream>>>((const float4*)hs, A, (ROWS * D_K) / 4);
    conv_w<<<dim3(16, 8, 2), 256, 0, stream>>>(Wd, Wh, Bt);
    prep_small<<<1, 1024, 0, stream>>>(bd, bh, Wc, bias, wcp);
    gemm_scores<<<dim3(8, 128), 256, 0, stream>>>(A, Bt, bias, wcp, sd, sh);
    bcast<<<ROWS, 256, 0, stream>>>(sd, sh, bc, out);
}

// Round 2
// 101.252 us; speedup vs baseline: 1.1901x; 1.1901x over previous
//
#include <hip/hip_runtime.h>

// Problem constants
#define D_K   1024      // hidden dim (GEMM K)
#define ROWS  16384     // B*L
#define MLP   500
#define NEG   0.01f

// GEMM geometry
#define BM    256
#define BN    256
#define BK    32
#define NBUF  4
#define NT    (D_K / BK)        // 32 K-tiles
#define SLOT_B (BM * BK * 2)    // 16384 bytes per tile per matrix

typedef __bf16 bf16x8 __attribute__((ext_vector_type(8)));
typedef float  f32x4  __attribute__((ext_vector_type(4)));

#define GL(p) ((const __attribute__((address_space(1))) void*)(p))
#define LD(p) ((__attribute__((address_space(3))) void*)(p))

__device__ __forceinline__ ushort f2bf(float f) {
    union { float f; unsigned u; } v; v.f = f;
    unsigned u = v.u;
    unsigned r = (u + 0x7FFFu + ((u >> 16) & 1u)) >> 16;   // RNE
    return (ushort)r;
}

// T2 swizzle: involution on tile byte offsets. 64B rows; spreads 8 consecutive
// rows across 8 distinct 16B bank positions (2 lanes/bank = free, m136).
__device__ __forceinline__ unsigned swz(unsigned x) {
    return x ^ (((x >> 7) & 3u) << 4);
}

// ---------------- fused prep: hidden f32->bf16, W transpose+pad, bias/Wc pad, zero scores ----
__global__ __launch_bounds__(256) void prep_all(const float* __restrict__ hs,
                                                const float* __restrict__ Wd,
                                                const float* __restrict__ bd,
                                                const float* __restrict__ Wh,
                                                const float* __restrict__ bh,
                                                const float* __restrict__ Wc,
                                                ushort* __restrict__ A,
                                                ushort* __restrict__ Bt,
                                                float* __restrict__ bias_pad,
                                                float* __restrict__ wc_pad,
                                                float4* __restrict__ zero_area) {
    __shared__ ushort tbuf[64][72];
    const int bid = blockIdx.x, tid = threadIdx.x;
    if (bid < 2048) {
        // hidden f32 -> bf16 (16B/lane read, 8B write)
        const float4* in = (const float4*)hs;
        const int n4 = ROWS * D_K / 4;
        for (int i = bid * 256 + tid; i < n4; i += 2048 * 256) {
            float4 f = in[i];
            ushort4 o;
            o.x = f2bf(f.x); o.y = f2bf(f.y); o.z = f2bf(f.z); o.w = f2bf(f.w);
            ((ushort4*)A)[i] = o;
        }
    } else if (bid < 2304) {
        // W [1024][500] -> Bt bf16 [1024][1024] transposed + zero-padded
        int b = bid - 2048;
        const int z = b >> 7; b &= 127;
        const int kx = b & 15, ny = b >> 4;
        const float* W = z ? Wh : Wd;
        const int k0 = kx * 64, n0 = ny * 64;
        const int c = tid & 63, r4 = tid >> 6;
        for (int r = r4; r < 64; r += 4) {
            int n = n0 + c;
            float v = (n < MLP) ? W[(size_t)(k0 + r) * MLP + n] : 0.f;
            tbuf[c][r] = f2bf(v);
        }
        __syncthreads();
        const int nbase = z * 512 + n0;
        for (int rr = r4; rr < 64; rr += 4)
            Bt[(size_t)(nbase + rr) * D_K + k0 + c] = tbuf[rr][c];
    } else if (bid < 2308) {
        // pad bias + Wc
        int n = (bid - 2304) * 256 + tid;   // [0,1024)
        float bv = 0.f, w0 = 0.f, w1 = 0.f;
        if (n < 512) {
            if (n < MLP) { bv = bd[n]; w0 = Wc[n * 2]; w1 = Wc[n * 2 + 1]; }
        } else {
            int m = n - 512;
            if (m < MLP) { bv = bh[m]; w0 = Wc[(MLP + m) * 2]; w1 = Wc[(MLP + m) * 2 + 1]; }
        }
        bias_pad[n] = bv; wc_pad[n * 2] = w0; wc_pad[n * 2 + 1] = w1;
    } else {
        // zero sd+sh (256 KB contiguous)
        int i = (bid - 2308) * 256 + tid;   // [0,16384) float4
        zero_area[i] = make_float4(0.f, 0.f, 0.f, 0.f);
    }
}

// ---------------- 256x256 GEMM, 4-deep ring, counted vmcnt, fused epilogue ----------------
// C[row,n] = A[row,:] . Bt[n,:]; h = leakyrelu(C+bias); scores += h . wc  (atomic)
__global__ __launch_bounds__(512) void gemm_scores(const ushort* __restrict__ A,
                                                   const ushort* __restrict__ Bt,
                                                   const float* __restrict__ bias,
                                                   const float* __restrict__ wc,
                                                   float* __restrict__ sd,
                                                   float* __restrict__ sh) {
    __shared__ ushort As[NBUF * BM * BK];   // 64 KB
    __shared__ ushort Bs[NBUF * BN * BK];   // 64 KB
    const int tid  = threadIdx.x;
    const int lane = tid & 63;
    const int wave = tid >> 6;            // 0..7
    const int wm = wave >> 2, wn = wave & 3;

    // XCD-aware bijective swizzle: 256 blocks, 8 XCDs -> 32 consecutive per XCD,
    // so the 4 bn-blocks sharing an A panel land on one XCD's L2.
    const int flat  = blockIdx.y * gridDim.x + blockIdx.x;
    const int sflat = (flat & 7) * 32 + (flat >> 3);
    const int bn = sflat & 3, bm = sflat >> 2;
    const size_t row0 = (size_t)bm * BM;
    const int col0 = bn * BN;

    char* AsB = (char*)As;
    char* BsB = (char*)Bs;

    // Staging: per thread 2x16B per matrix per tile. Linear LDS dest (gload_lds
    // requirement), inverse-swizzled global source (rule #21 / m173 pattern).
    const ushort* aptr[2]; const ushort* bptr[2];
    unsigned ldst[2];
#pragma unroll
    for (int i = 0; i < 2; ++i) {
        unsigned x = (unsigned)wave * 2048u + (unsigned)i * 1024u + (unsigned)lane * 16u;
        ldst[i] = x;
        unsigned sx = swz(x);
        unsigned row = sx >> 6, cb = sx & 63;          // row in tile, byte within 64B row
        aptr[i] = A  + (row0 + row) * D_K + (cb >> 1);
        bptr[i] = Bt + (size_t)((unsigned)col0 + row) * D_K + (cb >> 1);
    }

    // ds_read fragment offsets (swizzled)
    const unsigned l15 = lane & 15, c16 = (unsigned)(lane >> 4) * 16u;
    unsigned yA[8], yB[4];
#pragma unroll
    for (int m = 0; m < 8; ++m) {
        unsigned y = ((unsigned)(wm * 128 + m * 16) + l15) * 64u + c16;
        yA[m] = swz(y);
    }
#pragma unroll
    for (int n = 0; n < 4; ++n) {
        unsigned y = ((unsigned)(wn * 64 + n * 16) + l15) * 64u + c16;
        yB[n] = swz(y);
    }

    f32x4 acc[8][4] = {};

#define STAGE(t) { const int sl_ = (t) & 3;                                                          \
    __builtin_amdgcn_global_load_lds(GL(aptr[0] + (t) * BK), LD(AsB + sl_ * SLOT_B + ldst[0]), 16, 0, 0); \
    __builtin_amdgcn_global_load_lds(GL(bptr[0] + (t) * BK), LD(BsB + sl_ * SLOT_B + ldst[0]), 16, 0, 0); \
    __builtin_amdgcn_global_load_lds(GL(aptr[1] + (t) * BK), LD(AsB + sl_ * SLOT_B + ldst[1]), 16, 0, 0); \
    __builtin_amdgcn_global_load_lds(GL(bptr[1] + (t) * BK), LD(BsB + sl_ * SLOT_B + ldst[1]), 16, 0, 0); }

    STAGE(0); STAGE(1); STAGE(2);   // 12 loads in flight (3 tiles ahead)

    for (int t = 0; t < NT; ++t) {
        if (t + 3 < NT) {
            STAGE(t + 3);                                    // 16 in flight
            asm volatile("s_waitcnt vmcnt(8)" ::: "memory"); // drain tile t+1; keep 2 tiles flying
        } else if (t + 2 < NT) {
            asm volatile("s_waitcnt vmcnt(4)" ::: "memory");
        } else {
            asm volatile("s_waitcnt vmcnt(0)" ::: "memory");
        }
        __builtin_amdgcn_s_barrier();        // all waves' tile-t (and t+1) loads landed
        __builtin_amdgcn_sched_barrier(0);   // pin: no ds_read hoists above the barrier
        const int sl = t & 3;
        bf16x8 bf[4];
#pragma unroll
        for (int n = 0; n < 4; ++n)
            bf[n] = *(const bf16x8*)(BsB + sl * SLOT_B + yB[n]);
        __builtin_amdgcn_s_setprio(1);
#pragma unroll
        for (int m = 0; m < 8; ++m) {
            bf16x8 af = *(const bf16x8*)(AsB + sl * SLOT_B + yA[m]);
#pragma unroll
            for (int n = 0; n < 4; ++n)
                acc[m][n] = __builtin_amdgcn_mfma_f32_16x16x32_bf16(af, bf[n], acc[m][n], 0, 0, 0);
        }
        __builtin_amdgcn_s_setprio(0);
        __builtin_amdgcn_s_barrier();        // tile-t reads done before its slot is re-staged
    }

    // Epilogue: bias + leakyrelu + rank-2 contraction, 16-lane reduce, atomic add.
    // C/D layout: col = lane&15, row = (lane>>4)*4 + reg  [m89-verified]
    float bv[4], w0v[4], w1v[4];
#pragma unroll
    for (int nf = 0; nf < 4; ++nf) {
        int c = col0 + wn * 64 + nf * 16 + (int)l15;
        bv[nf] = bias[c]; w0v[nf] = wc[2 * c]; w1v[nf] = wc[2 * c + 1];
    }
    float* S = (bn < 2) ? sd : sh;
#pragma unroll
    for (int mf = 0; mf < 8; ++mf) {
        size_t rowb = row0 + (size_t)(wm * 128 + mf * 16 + (lane >> 4) * 4);
#pragma unroll
        for (int r = 0; r < 4; ++r) {
            float s0 = 0.f, s1 = 0.f;
#pragma unroll
            for (int nf = 0; nf < 4; ++nf) {
                float h = acc[mf][nf][r] + bv[nf];
                h = (h > 0.f) ? h : NEG * h;
                s0 += h * w0v[nf]; s1 += h * w1v[nf];
            }
#pragma unroll
            for (int m = 1; m < 16; m <<= 1) {
                s0 += __shfl_xor(s0, m, 64);
                s1 += __shfl_xor(s1, m, 64);
            }
            if (l15 == 0) {
                atomicAdd(&S[(rowb + r) * 2 + 0], s0);
                atomicAdd(&S[(rowb + r) * 2 + 1], s1);
            }
        }
    }
#undef STAGE
}

// ---------------- broadcast add: out[b,i,j,c] = sd[b,i,c] + sh[b,j,c] + bc[c] ----------------
__global__ __launch_bounds__(256) void bcast(const float* __restrict__ sd,
                                             const float* __restrict__ sh,
                                             const float* __restrict__ bc,
                                             float* __restrict__ out) {
    const int bi = blockIdx.x;            // b*1024 + i
    const int b  = bi >> 10;
    const float v0 = sd[bi * 2 + 0] + bc[0];
    const float v1 = sd[bi * 2 + 1] + bc[1];
    const float4* shrow = (const float4*)(sh + (size_t)b * 2048);
    float4* orow = (float4*)(out + (size_t)bi * 2048);
#pragma unroll
    for (int t = threadIdx.x; t < 512; t += 256) {
        float4 s = shrow[t];
        float4 o;
        o.x = v0 + s.x; o.y = v1 + s.y; o.z = v0 + s.z; o.w = v1 + s.w;
        orow[t] = o;
    }
}

extern "C" void kernel_launch(void* const* d_in, const int* in_sizes, int n_in,
                              void* d_out, int out_size, void* d_ws, size_t ws_size,
                              hipStream_t stream) {
    const float* hs = (const float*)d_in[0];
    const float* Wd = (const float*)d_in[1];
    const float* bd = (const float*)d_in[2];
    const float* Wh = (const float*)d_in[3];
    const float* bh = (const float*)d_in[4];
    const float* Wc = (const float*)d_in[5];
    const float* bc = (const float*)d_in[6];
    float* out = (float*)d_out;

    char* ws = (char*)d_ws;
    ushort* A    = (ushort*)(ws);                 // 33,554,432 B
    ushort* Bt   = (ushort*)(ws + 33554432);      //  2,097,152 B
    float*  bias = (float*) (ws + 35651584);      //  4 KB
    float*  wcp  = (float*) (ws + 35655680);      //  8 KB
    float*  sd   = (float*) (ws + 35663872);      //  128 KB
    float*  sh   = (float*) (ws + 35794944);      //  128 KB

    prep_all<<<2372, 256, 0, stream>>>(hs, Wd, bd, Wh, bh, Wc, A, Bt, bias, wcp, (float4*)sd);
    gemm_scores<<<dim3(4, 64), 512, 0, stream>>>(A, Bt, bias, wcp, sd, sh);
    bcast<<<ROWS, 256, 0, stream>>>(sd, sh, bc, out);
}

// Round 3
// 95.225 us; speedup vs baseline: 1.2654x; 1.0633x over previous
//
#include <hip/hip_runtime.h>

// Problem constants
#define D_K   1024      // hidden dim (GEMM K)
#define ROWS  16384     // B*L
#define MLP   500
#define NEG   0.01f

// GEMM geometry
#define BM    256
#define BN    256
#define BK    32
#define NT    (D_K / BK)        // 32 K-tiles
#define SLOT_B (BM * BK * 2)    // 16384 bytes per tile per matrix

typedef __bf16 bf16x8 __attribute__((ext_vector_type(8)));
typedef float  f32x4  __attribute__((ext_vector_type(4)));

#define GL(p) ((const __attribute__((address_space(1))) void*)(p))
#define LD(p) ((__attribute__((address_space(3))) void*)(p))

__device__ __forceinline__ ushort f2bf(float f) {
    union { float f; unsigned u; } v; v.f = f;
    unsigned u = v.u;
    unsigned r = (u + 0x7FFFu + ((u >> 16) & 1u)) >> 16;   // RNE
    return (ushort)r;
}

// T2 swizzle (r2-verified involution): XOR byte bits 4-5 with bits 7-8.
// Read pattern (64B rows, 16 lanes stride-64B) lands 2 lanes/bank = free (m136).
__device__ __forceinline__ unsigned swz(unsigned x) {
    return x ^ (((x >> 7) & 3u) << 4);
}

// ---------------- fused prep: hidden f32->bf16, W transpose+pad, bias/Wc pad, zero scores ----
__global__ __launch_bounds__(256) void prep_all(const float* __restrict__ hs,
                                                const float* __restrict__ Wd,
                                                const float* __restrict__ bd,
                                                const float* __restrict__ Wh,
                                                const float* __restrict__ bh,
                                                const float* __restrict__ Wc,
                                                ushort* __restrict__ A,
                                                ushort* __restrict__ Bt,
                                                float* __restrict__ bias_pad,
                                                float* __restrict__ wc_pad,
                                                float4* __restrict__ zero_area) {
    __shared__ ushort tbuf[64][72];
    const int bid = blockIdx.x, tid = threadIdx.x;
    if (bid < 2048) {
        // hidden f32 -> bf16 (16B/lane read, 8B write)
        const float4* in = (const float4*)hs;
        const int n4 = ROWS * D_K / 4;
        for (int i = bid * 256 + tid; i < n4; i += 2048 * 256) {
            float4 f = in[i];
            ushort4 o;
            o.x = f2bf(f.x); o.y = f2bf(f.y); o.z = f2bf(f.z); o.w = f2bf(f.w);
            ((ushort4*)A)[i] = o;
        }
    } else if (bid < 2304) {
        // W [1024][500] -> Bt bf16 [1024][1024] transposed + zero-padded
        int b = bid - 2048;
        const int z = b >> 7; b &= 127;
        const int kx = b & 15, ny = b >> 4;
        const float* W = z ? Wh : Wd;
        const int k0 = kx * 64, n0 = ny * 64;
        const int c = tid & 63, r4 = tid >> 6;
        for (int r = r4; r < 64; r += 4) {
            int n = n0 + c;
            float v = (n < MLP) ? W[(size_t)(k0 + r) * MLP + n] : 0.f;
            tbuf[c][r] = f2bf(v);
        }
        __syncthreads();
        const int nbase = z * 512 + n0;
        for (int rr = r4; rr < 64; rr += 4)
            Bt[(size_t)(nbase + rr) * D_K + k0 + c] = tbuf[rr][c];
    } else if (bid < 2308) {
        // pad bias + Wc
        int n = (bid - 2304) * 256 + tid;   // [0,1024)
        float bv = 0.f, w0 = 0.f, w1 = 0.f;
        if (n < 512) {
            if (n < MLP) { bv = bd[n]; w0 = Wc[n * 2]; w1 = Wc[n * 2 + 1]; }
        } else {
            int m = n - 512;
            if (m < MLP) { bv = bh[m]; w0 = Wc[(MLP + m) * 2]; w1 = Wc[(MLP + m) * 2 + 1]; }
        }
        bias_pad[n] = bv; wc_pad[n * 2] = w0; wc_pad[n * 2 + 1] = w1;
    } else {
        // zero sd+sh (256 KB contiguous)
        int i = (bid - 2308) * 256 + tid;   // [0,16384) float4
        zero_area[i] = make_float4(0.f, 0.f, 0.f, 0.f);
    }
}

// ---------------- 256x256 GEMM, 4-slot ring, 2 phases/K-tile, counted vmcnt ----------------
// C[row,n] = A[row,:] . Bt[n,:]; h = leakyrelu(C+bias); scores += h . wc  (atomic)
__global__ __launch_bounds__(512, 2) void gemm_scores(const ushort* __restrict__ A,
                                                      const ushort* __restrict__ Bt,
                                                      const float* __restrict__ bias,
                                                      const float* __restrict__ wc,
                                                      float* __restrict__ sd,
                                                      float* __restrict__ sh) {
    __shared__ ushort As[4 * BM * BK];   // 64 KB
    __shared__ ushort Bs[4 * BN * BK];   // 64 KB
    const int tid  = threadIdx.x;
    const int lane = tid & 63;
    const int wave = tid >> 6;            // 0..7
    const int wm = wave >> 2, wn = wave & 3;

    // XCD-aware bijective swizzle: 256 blocks, 8 XCDs -> 32 consecutive per XCD,
    // so the 4 bn-blocks sharing an A panel land on one XCD's L2.
    const int flat  = blockIdx.y * gridDim.x + blockIdx.x;
    const int sflat = (flat & 7) * 32 + (flat >> 3);
    const int bn = sflat & 3, bm = sflat >> 2;
    const size_t row0 = (size_t)bm * BM;
    const int col0 = bn * BN;

    char* AsB = (char*)As;
    char* BsB = (char*)Bs;

    // Staging: per thread 2x16B per matrix per tile. Linear LDS dest (gload_lds
    // requirement), inverse-swizzled global source (rule #21 / m173 pattern).
    const ushort* aptr[2]; const ushort* bptr[2];
    unsigned ldst[2];
#pragma unroll
    for (int i = 0; i < 2; ++i) {
        unsigned x = (unsigned)wave * 1024u + (unsigned)i * 8192u + (unsigned)lane * 16u;
        ldst[i] = x;
        unsigned sx = swz(x);
        unsigned row = sx >> 6, cb = sx & 63;          // row in tile, byte within 64B row
        aptr[i] = A  + (row0 + row) * D_K + (cb >> 1);
        bptr[i] = Bt + (size_t)((unsigned)col0 + row) * D_K + (cb >> 1);
    }

    // ds_read fragment offsets (swizzled)
    const unsigned l15 = lane & 15, c16 = (unsigned)(lane >> 4) * 16u;
    unsigned yA[8], yB[4];
#pragma unroll
    for (int m = 0; m < 8; ++m) {
        unsigned y = ((unsigned)(wm * 128 + m * 16) + l15) * 64u + c16;
        yA[m] = swz(y);
    }
#pragma unroll
    for (int n = 0; n < 4; ++n) {
        unsigned y = ((unsigned)(wn * 64 + n * 16) + l15) * 64u + c16;
        yB[n] = swz(y);
    }

    f32x4 acc[8][4] = {};

#define STAGE_A(t) { const int sl_ = (t) & 3;                                                             \
    __builtin_amdgcn_global_load_lds(GL(aptr[0] + (t) * BK), LD(AsB + sl_ * SLOT_B + ldst[0]), 16, 0, 0); \
    __builtin_amdgcn_global_load_lds(GL(aptr[1] + (t) * BK), LD(AsB + sl_ * SLOT_B + ldst[1]), 16, 0, 0); }
#define STAGE_B(t) { const int sl_ = (t) & 3;                                                             \
    __builtin_amdgcn_global_load_lds(GL(bptr[0] + (t) * BK), LD(BsB + sl_ * SLOT_B + ldst[0]), 16, 0, 0); \
    __builtin_amdgcn_global_load_lds(GL(bptr[1] + (t) * BK), LD(BsB + sl_ * SLOT_B + ldst[1]), 16, 0, 0); }

    // Prologue: 3 tiles in flight, verify tile 0 landed.
    STAGE_A(0); STAGE_B(0);
    STAGE_A(1); STAGE_B(1);
    STAGE_A(2); STAGE_B(2);
    asm volatile("s_waitcnt vmcnt(8)" ::: "memory");
    __builtin_amdgcn_s_barrier();

    for (int t = 0; t < NT; ++t) {
        const int sl = t & 3;
        char* Asl = AsB + sl * SLOT_B;
        char* Bsl = BsB + sl * SLOT_B;

        // ================= phase A: frags(m0-3 x n0-3) + stage A-half(t+3) =================
        bf16x8 bf[4], af[4];
#pragma unroll
        for (int n = 0; n < 4; ++n) bf[n] = *(const bf16x8*)(Bsl + yB[n]);
#pragma unroll
        for (int m = 0; m < 4; ++m) af[m] = *(const bf16x8*)(Asl + yA[m]);
        if (t + 3 < NT) STAGE_A(t + 3);
        __builtin_amdgcn_s_barrier();
        asm volatile("s_waitcnt lgkmcnt(0)" ::: "memory");
        __builtin_amdgcn_sched_barrier(0);
        __builtin_amdgcn_s_setprio(1);
#pragma unroll
        for (int m = 0; m < 4; ++m)
#pragma unroll
            for (int n = 0; n < 4; ++n)
                acc[m][n] = __builtin_amdgcn_mfma_f32_16x16x32_bf16(af[m], bf[n], acc[m][n], 0, 0, 0);
        __builtin_amdgcn_s_setprio(0);
        __builtin_amdgcn_sched_barrier(0);
        __builtin_amdgcn_s_barrier();

        // ================= phase B: frags(m4-7, reuse bf) + stage B-half(t+3) + vmcnt =======
        bf16x8 ag[4];
#pragma unroll
        for (int m = 0; m < 4; ++m) ag[m] = *(const bf16x8*)(Asl + yA[m + 4]);
        if (t + 3 < NT) STAGE_B(t + 3);
        // Counted wait: tile t+1 must be landed before next iteration's reads.
        if (t + 3 < NT)      asm volatile("s_waitcnt vmcnt(8)" ::: "memory");
        else if (t + 2 < NT) asm volatile("s_waitcnt vmcnt(4)" ::: "memory");
        else if (t + 1 < NT) asm volatile("s_waitcnt vmcnt(0)" ::: "memory");
        __builtin_amdgcn_s_barrier();
        asm volatile("s_waitcnt lgkmcnt(0)" ::: "memory");
        __builtin_amdgcn_sched_barrier(0);
        __builtin_amdgcn_s_setprio(1);
#pragma unroll
        for (int m = 0; m < 4; ++m)
#pragma unroll
            for (int n = 0; n < 4; ++n)
                acc[m + 4][n] = __builtin_amdgcn_mfma_f32_16x16x32_bf16(ag[m], bf[n], acc[m + 4][n], 0, 0, 0);
        __builtin_amdgcn_s_setprio(0);
        __builtin_amdgcn_sched_barrier(0);
        __builtin_amdgcn_s_barrier();
    }
#undef STAGE_A
#undef STAGE_B

    // Epilogue: bias + leakyrelu + rank-2 contraction, 16-lane reduce, atomic add.
    // C/D layout: col = lane&15, row = (lane>>4)*4 + reg  [m89-verified]
    float bv[4], w0v[4], w1v[4];
#pragma unroll
    for (int nf = 0; nf < 4; ++nf) {
        int c = col0 + wn * 64 + nf * 16 + (int)l15;
        bv[nf] = bias[c]; w0v[nf] = wc[2 * c]; w1v[nf] = wc[2 * c + 1];
    }
    float* S = (bn < 2) ? sd : sh;
#pragma unroll
    for (int mf = 0; mf < 8; ++mf) {
        size_t rowb = row0 + (size_t)(wm * 128 + mf * 16 + (lane >> 4) * 4);
#pragma unroll
        for (int r = 0; r < 4; ++r) {
            float s0 = 0.f, s1 = 0.f;
#pragma unroll
            for (int nf = 0; nf < 4; ++nf) {
                float h = acc[mf][nf][r] + bv[nf];
                h = (h > 0.f) ? h : NEG * h;
                s0 += h * w0v[nf]; s1 += h * w1v[nf];
            }
#pragma unroll
            for (int m = 1; m < 16; m <<= 1) {
                s0 += __shfl_xor(s0, m, 64);
                s1 += __shfl_xor(s1, m, 64);
            }
            if (l15 == 0) {
                atomicAdd(&S[(rowb + r) * 2 + 0], s0);
                atomicAdd(&S[(rowb + r) * 2 + 1], s1);
            }
        }
    }
}

// ---------------- broadcast add: out[b,i,j,c] = sd[b,i,c] + sh[b,j,c] + bc[c] ----------------
__global__ __launch_bounds__(256) void bcast(const float* __restrict__ sd,
                                             const float* __restrict__ sh,
                                             const float* __restrict__ bc,
                                             float* __restrict__ out) {
    const int bi = blockIdx.x;            // b*1024 + i
    const int b  = bi >> 10;
    const float v0 = sd[bi * 2 + 0] + bc[0];
    const float v1 = sd[bi * 2 + 1] + bc[1];
    const float4* shrow = (const float4*)(sh + (size_t)b * 2048);
    float4* orow = (float4*)(out + (size_t)bi * 2048);
#pragma unroll
    for (int t = threadIdx.x; t < 512; t += 256) {
        float4 s = shrow[t];
        float4 o;
        o.x = v0 + s.x; o.y = v1 + s.y; o.z = v0 + s.z; o.w = v1 + s.w;
        orow[t] = o;
    }
}

extern "C" void kernel_launch(void* const* d_in, const int* in_sizes, int n_in,
                              void* d_out, int out_size, void* d_ws, size_t ws_size,
                              hipStream_t stream) {
    const float* hs = (const float*)d_in[0];
    const float* Wd = (const float*)d_in[1];
    const float* bd = (const float*)d_in[2];
    const float* Wh = (const float*)d_in[3];
    const float* bh = (const float*)d_in[4];
    const float* Wc = (const float*)d_in[5];
    const float* bc = (const float*)d_in[6];
    float* out = (float*)d_out;

    char* ws = (char*)d_ws;
    ushort* A    = (ushort*)(ws);                 // 33,554,432 B
    ushort* Bt   = (ushort*)(ws + 33554432);      //  2,097,152 B
    float*  bias = (float*) (ws + 35651584);      //  4 KB
    float*  wcp  = (float*) (ws + 35655680);      //  8 KB
    float*  sd   = (float*) (ws + 35663872);      //  128 KB
    float*  sh   = (float*) (ws + 35794944);      //  128 KB

    prep_all<<<2372, 256, 0, stream>>>(hs, Wd, bd, Wh, bh, Wc, A, Bt, bias, wcp, (float4*)sd);
    gemm_scores<<<dim3(4, 64), 512, 0, stream>>>(A, Bt, bias, wcp, sd, sh);
    bcast<<<ROWS, 256, 0, stream>>>(sd, sh, bc, out);
}